// Round 1
// baseline (158.582 us; speedup 1.0000x reference)
//
#include <hip/hip_runtime.h>
#include <hip/hip_bf16.h>
#include <cmath>

#define DIM 128
#define HEADS 8
#define NBATCH 2
#define NQ 6400   /* 80*80 */
#define NKV 1600  /* 40*40 */
#define NC 50     /* kv chunks of 32 */
#define BN_EPS 1e-5f
#define LOG2E 1.4426950408889634f

typedef __bf16 bf16_t;
typedef __attribute__((ext_vector_type(8))) __bf16 bf16x8;
typedef __attribute__((ext_vector_type(16))) float f32x16;

union BF8U { bf16x8 v; unsigned u[4]; };

// pack two f32 -> packed bf16 (a->lo, b->hi); lowers to v_cvt_pk_bf16_f32 (RNE)
__device__ inline unsigned packbf2(float a, float b) {
  union { __hip_bfloat162 v; unsigned u; } r;
  r.v = __float22bfloat162_rn(make_float2(a, b));
  return r.u;
}

__device__ inline unsigned short f2bf(float v) {
  unsigned u = __float_as_uint(v);
  return (unsigned short)((u + 0x7FFFu + ((u >> 16) & 1u)) >> 16);
}

// ---------------------------------------------------------------------------
// Fused q + (sr -> bn -> relu -> k -> v) GEMMs, reading f32 x and f32 weights
// DIRECTLY with inline bf16 casts (v_cvt_pk_bf16_f32 in regs).
// prep_all (transpose / im2col / weight-cast / denom-fill) is ELIMINATED:
//  - q A-frags: lane = token, 8 channel-strided f32 loads per step; for a
//    fixed channel the 32 lanes hit 32 consecutive dwords -> coalesced.
//  - sr GEMM: 4 accumulation passes over (ky,kx), K=128 each; A-element is
//    x[c][2i+ky][2j+kx], B-element srw[o][c][ky][kx] (stride-4 gather).
//    Identical math to the old im2col K=512 pass (reordered f32 sum).
//  - Vp denominator rows written by the sr block owning the chunk.
// blocks [0,50): sr->k->v.  blocks [50,250): q tile, *SCALE*log2e.
// ---------------------------------------------------------------------------
__global__ __launch_bounds__(256) void mgemm_qsrkv(
    const float* __restrict__ x,
    const float* __restrict__ qw, const float* __restrict__ kw,
    const float* __restrict__ vw, const float* __restrict__ srw,
    const float* __restrict__ q_b, const float* __restrict__ sr_b,
    const float* __restrict__ k_b, const float* __restrict__ v_b,
    const float* __restrict__ bng, const float* __restrict__ bnb,
    const float* __restrict__ bnm, const float* __restrict__ bnv,
    unsigned short* __restrict__ Qb,
    unsigned short* __restrict__ Kp, unsigned short* __restrict__ Vp,
    float sl)
{
  __shared__ __align__(16) unsigned short xs[32][136];
  int t = threadIdx.x;
  int ln = t & 31, hf = (t >> 5) & 1, wid = t >> 6;
  int b = blockIdx.y;
  int o = wid * 32 + ln;

  if (blockIdx.x < 50) {             // ---- sr -> k -> v part ----
    int cid = blockIdx.x;
    int s0 = cid * 32;
    int s = s0 + ln;                 // this lane's kv token
    int i = s / 40, j = s % 40;
    const float* xb = x + (size_t)b * DIM * NQ;

    f32x16 acc = {};
#pragma unroll
    for (int p = 0; p < 4; ++p) {    // (ky,kx) accumulation passes
      int ky = p >> 1, kx = p & 1;
      const float* xpos = xb + (2 * i + ky) * 80 + (2 * j + kx);
      const float* wrow = srw + (size_t)o * 512 + p;
#pragma unroll
      for (int c0 = 0; c0 < 128; c0 += 16) {
        int cb = c0 + hf * 8;
        BF8U af, bf;
#pragma unroll
        for (int m = 0; m < 4; ++m) {
          af.u[m] = packbf2(xpos[(size_t)(cb + 2 * m) * NQ],
                            xpos[(size_t)(cb + 2 * m + 1) * NQ]);
          bf.u[m] = packbf2(wrow[(size_t)(cb + 2 * m) * 4],
                            wrow[(size_t)(cb + 2 * m + 1) * 4]);
        }
        acc = __builtin_amdgcn_mfma_f32_32x32x16_bf16(af.v, bf.v, acc, 0, 0, 0);
      }
    }
    float bv = sr_b[o];
    float inv = bng[o] / sqrtf(bnv[o] + BN_EPS);
    float b2 = bnb[o] - bnm[o] * inv;
#pragma unroll
    for (int g = 0; g < 4; ++g)
#pragma unroll
      for (int jj = 0; jj < 4; ++jj) {
        int sr = 8 * g + 4 * hf + jj;
        xs[sr][o] = f2bf(fmaxf((acc[4 * g + jj] + bv) * inv + b2, 0.f));
      }
    __syncthreads();

    // k + v GEMMs (C=128) off the LDS tile, f32 weights cast inline
    const unsigned short* ar2 = &xs[ln][hf * 8];
    const float* kwrow = kw + (size_t)o * DIM;
    const float* vwrow = vw + (size_t)o * DIM;
    f32x16 ka = {}, va = {};
#pragma unroll
    for (int c0 = 0; c0 < 128; c0 += 16) {
      int cb = c0 + hf * 8;
      bf16x8 af = *(const bf16x8*)&ar2[c0];
      BF8U kb, vb;
      float4 k0 = *(const float4*)(kwrow + cb);
      float4 k1 = *(const float4*)(kwrow + cb + 4);
      float4 v0 = *(const float4*)(vwrow + cb);
      float4 v1 = *(const float4*)(vwrow + cb + 4);
      kb.u[0] = packbf2(k0.x, k0.y); kb.u[1] = packbf2(k0.z, k0.w);
      kb.u[2] = packbf2(k1.x, k1.y); kb.u[3] = packbf2(k1.z, k1.w);
      vb.u[0] = packbf2(v0.x, v0.y); vb.u[1] = packbf2(v0.z, v0.w);
      vb.u[2] = packbf2(v1.x, v1.y); vb.u[3] = packbf2(v1.z, v1.w);
      ka = __builtin_amdgcn_mfma_f32_32x32x16_bf16(af, kb.v, ka, 0, 0, 0);
      va = __builtin_amdgcn_mfma_f32_32x32x16_bf16(af, vb.v, va, 0, 0, 0);
    }
    int hloc = o >> 4, d = o & 15;
    {
      float kb2 = k_b[o];
      size_t CB = (((size_t)b * HEADS + hloc) * NC + cid) * 512;
#pragma unroll
      for (int g = 0; g < 4; ++g)
#pragma unroll
        for (int jj = 0; jj < 4; ++jj) {
          int sl2 = 8 * g + 4 * hf + jj;
          Kp[CB + sl2 * 16 + d] = f2bf(ka[4 * g + jj] + kb2);
        }
    }
    {
      float vb2 = v_b[o];
      size_t CB = (((size_t)b * HEADS + hloc) * NC + cid) * 1024;
      uint4 w0, w1;
      w0.x = packbf2(va[0] + vb2, va[1] + vb2);
      w0.y = packbf2(va[2] + vb2, va[3] + vb2);
      w0.z = packbf2(va[4] + vb2, va[5] + vb2);
      w0.w = packbf2(va[6] + vb2, va[7] + vb2);
      w1.x = packbf2(va[8] + vb2, va[9] + vb2);
      w1.y = packbf2(va[10] + vb2, va[11] + vb2);
      w1.z = packbf2(va[12] + vb2, va[13] + vb2);
      w1.w = packbf2(va[14] + vb2, va[15] + vb2);
      *(uint4*)&Vp[CB + d * 16 + hf * 8] = w0;       // va block
      *(uint4*)&Vp[CB + 512 + d * 16 + hf * 8] = w1; // vb block
    }
    // Vp lane-16 (denominator) rows for this (b, chunk), all 8 heads
    {
      int hh = t >> 5, pos = t & 31;
      size_t addr = (((size_t)b * HEADS + hh) * NC + cid) * 1024 + 256 +
                    ((pos & 16) ? 512 : 0) + (pos & 15);
      Vp[addr] = 0x3F80;               // 1.0 bf16
    }
  } else {                           // ---- q part (C = 128) ----
    int s0 = (blockIdx.x - 50) * 32;
    int s = s0 + ln;                 // this lane's q token
    const float* xcol = x + (size_t)b * DIM * NQ + s;
    const float* qwrow = qw + (size_t)o * DIM;
    f32x16 acc = {};
#pragma unroll
    for (int c0 = 0; c0 < 128; c0 += 16) {
      int cb = c0 + hf * 8;
      BF8U af, bf;
#pragma unroll
      for (int m = 0; m < 4; ++m)
        af.u[m] = packbf2(xcol[(size_t)(cb + 2 * m) * NQ],
                          xcol[(size_t)(cb + 2 * m + 1) * NQ]);
      float4 b0 = *(const float4*)(qwrow + cb);
      float4 b1 = *(const float4*)(qwrow + cb + 4);
      bf.u[0] = packbf2(b0.x, b0.y); bf.u[1] = packbf2(b0.z, b0.w);
      bf.u[2] = packbf2(b1.x, b1.y); bf.u[3] = packbf2(b1.z, b1.w);
      acc = __builtin_amdgcn_mfma_f32_32x32x16_bf16(af.v, bf.v, acc, 0, 0, 0);
    }
    float bv = q_b[o];
#pragma unroll
    for (int g = 0; g < 4; ++g)
#pragma unroll
      for (int jj = 0; jj < 4; ++jj) {
        int sq = s0 + 8 * g + 4 * hf + jj;
        Qb[((size_t)b * NQ + sq) * DIM + o] = f2bf((acc[4 * g + jj] + bv) * sl);
      }
  }
}

// ---------------------------------------------------------------------------
// MFMA attention, software-pipelined (unchanged from round-13 body). Launch
// bounds have NO min-waves arg: natural allocation (~40-56 VGPR) lets HW run
// up to the supply limit without spill. kv-split=2, fragment-major K/V,
// 2-deep prefetch, S one chunk ahead, dual accumulators.
// grid (50, 8, 4): z = b + 2*half. block 256.
// ---------------------------------------------------------------------------
__global__ __launch_bounds__(256) void attn_split(
    const bf16_t* __restrict__ Qb, const bf16_t* __restrict__ Kp,
    const bf16_t* __restrict__ Vp, unsigned short* __restrict__ Pb,
    float* __restrict__ Lsum)
{
  const int t = threadIdx.x;
  const int ln = t & 31, hf = (t >> 5) & 1, wid = t >> 6;
  const int h = blockIdx.y;
  const int b = blockIdx.z & 1, half = blockIdx.z >> 1;
  const int q0 = blockIdx.x * 128 + wid * 32;

  bf16x8 qf = *(const bf16x8*)&Qb[((size_t)b * NQ + q0 + ln) * DIM + h * 16 + hf * 8];
  const int bh = b * HEADS + h;
  const bf16_t* kc = &Kp[((size_t)bh * NC + half * 25) * 512 + ln * 16 + hf * 8];
  const bf16_t* vc = &Vp[((size_t)bh * NC + half * 25) * 1024 + ln * 16 + hf * 8];

  f32x16 acc0 = {}, acc1 = {};
  const f32x16 zero = {};

  bf16x8 kf0 = *(const bf16x8*)kc;
  bf16x8 va0 = *(const bf16x8*)vc;
  bf16x8 vb0 = *(const bf16x8*)(vc + 512);
  bf16x8 kf1 = *(const bf16x8*)(kc + 512);
  bf16x8 va1 = *(const bf16x8*)(vc + 1024);
  bf16x8 vb1 = *(const bf16x8*)(vc + 1536);

  f32x16 S0 = __builtin_amdgcn_mfma_f32_32x32x16_bf16(kf0, qf, zero, 0, 0, 0);

  for (int c = 0; c < 25; ++c) {
    int cn = (c + 2 < 25) ? c + 2 : 24;    // 2-deep prefetch (clamped)
    bf16x8 kf2 = *(const bf16x8*)(kc + (size_t)cn * 512);
    bf16x8 va2 = *(const bf16x8*)(vc + (size_t)cn * 1024);
    bf16x8 vb2 = *(const bf16x8*)(vc + (size_t)cn * 1024 + 512);

    f32x16 S1 = __builtin_amdgcn_mfma_f32_32x32x16_bf16(kf1, qf, zero, 0, 0, 0);

    BF8U f0, f1;
#pragma unroll
    for (int i = 0; i < 4; ++i) {
      f0.u[i] = packbf2(__builtin_amdgcn_exp2f(S0[2 * i]),
                        __builtin_amdgcn_exp2f(S0[2 * i + 1]));
      f1.u[i] = packbf2(__builtin_amdgcn_exp2f(S0[8 + 2 * i]),
                        __builtin_amdgcn_exp2f(S0[9 + 2 * i]));
    }

    acc0 = __builtin_amdgcn_mfma_f32_32x32x16_bf16(va0, f0.v, acc0, 0, 0, 0);
    acc1 = __builtin_amdgcn_mfma_f32_32x32x16_bf16(vb0, f1.v, acc1, 0, 0, 0);

    S0 = S1;
    kf0 = kf1; va0 = va1; vb0 = vb1;
    kf1 = kf2; va1 = va2; vb1 = vb2;
  }

  f32x16 acc;
#pragma unroll
  for (int i = 0; i < 16; ++i) acc[i] = acc0[i] + acc1[i];

  // acc: col q = ln, row d = (r&3)+8*(r>>2)+4*hf. Row16 (denom) = acc[8]@hf0.
  unsigned short* prow =
      &Pb[(size_t)(half * 2 + b) * (NQ * DIM) + (size_t)(q0 + ln) * DIM + h * 16 + 4 * hf];
  uint2 w0, w1;
  w0.x = packbf2(acc[0], acc[1]); w0.y = packbf2(acc[2], acc[3]);
  w1.x = packbf2(acc[4], acc[5]); w1.y = packbf2(acc[6], acc[7]);
  *(uint2*)&prow[0] = w0;
  *(uint2*)&prow[8] = w1;
  if (!hf)
    Lsum[(size_t)(half * 2 + b) * (HEADS * NQ) + (size_t)h * NQ + q0 + ln] = acc[8];
}

// ---------------------------------------------------------------------------
// proj_comb: fused combine (2 halves) + reference scramble + proj GEMM.
// proj weights read as f32 directly (inline bf16 cast) — no Wb buffer.
// grid (200, 2), block 256.
// ---------------------------------------------------------------------------
__global__ __launch_bounds__(256) void proj_comb(
    const unsigned short* __restrict__ Pb, const float* __restrict__ Lsum,
    const float* __restrict__ pw, const float* __restrict__ p_b,
    float* __restrict__ Out)
{
  __shared__ __align__(16) unsigned short As[32][136];
  int t = threadIdx.x;
  int b = blockIdx.y;
  int s0 = blockIdx.x * 32;

  {
    int tx = t & 31, cg = t >> 5;          // lane sweeps s (coalesced in f)
#pragma unroll
    for (int it = 0; it < 16; ++it) {
      int c = cg * 16 + it;
      int f = c * NQ + s0 + tx;            // flat att index = n*128 + h*16+d
      int n = f >> 7, hh = (f >> 4) & 7;
      float p0 = __uint_as_float((unsigned)Pb[(size_t)b * (NQ * DIM) + f] << 16);
      float p1 = __uint_as_float((unsigned)Pb[(size_t)(2 + b) * (NQ * DIM) + f] << 16);
      float L = Lsum[(size_t)b * (HEADS * NQ) + (size_t)hh * NQ + n] +
                Lsum[(size_t)(2 + b) * (HEADS * NQ) + (size_t)hh * NQ + n];
      As[tx][c] = f2bf((p0 + p1) / L);
    }
  }
  __syncthreads();

  int ln = t & 31, hf = (t >> 5) & 1, wid = t >> 6;
  int o = wid * 32 + ln;
  const float* brow = pw + (size_t)o * DIM;
  const unsigned short* arow = &As[ln][hf * 8];
  f32x16 acc = {};
#pragma unroll
  for (int c0 = 0; c0 < 128; c0 += 16) {
    int cb = c0 + hf * 8;
    bf16x8 af = *(const bf16x8*)&arow[c0];
    BF8U bf;
    float4 b0 = *(const float4*)(brow + cb);
    float4 b1 = *(const float4*)(brow + cb + 4);
    bf.u[0] = packbf2(b0.x, b0.y); bf.u[1] = packbf2(b0.z, b0.w);
    bf.u[2] = packbf2(b1.x, b1.y); bf.u[3] = packbf2(b1.z, b1.w);
    acc = __builtin_amdgcn_mfma_f32_32x32x16_bf16(af, bf.v, acc, 0, 0, 0);
  }
  float bv = p_b[o];
  float* obase = &Out[((size_t)b * DIM + o) * NQ + s0 + 4 * hf];
#pragma unroll
  for (int g = 0; g < 4; ++g) {
    float4 r;
    r.x = acc[4 * g + 0] + bv; r.y = acc[4 * g + 1] + bv;
    r.z = acc[4 * g + 2] + bv; r.w = acc[4 * g + 3] + bv;
    *(float4*)&obase[8 * g] = r;
  }
}

// ---------------------------------------------------------------------------
extern "C" void kernel_launch(void* const* d_in, const int* in_sizes, int n_in,
                              void* d_out, int out_size, void* d_ws, size_t ws_size,
                              hipStream_t stream)
{
  const float* x    = (const float*)d_in[0];
  const float* q_w  = (const float*)d_in[1];
  const float* q_b  = (const float*)d_in[2];
  const float* k_w  = (const float*)d_in[3];
  const float* k_b  = (const float*)d_in[4];
  const float* v_w  = (const float*)d_in[5];
  const float* v_b  = (const float*)d_in[6];
  const float* sr_w = (const float*)d_in[7];
  const float* sr_b = (const float*)d_in[8];
  const float* bng  = (const float*)d_in[9];
  const float* bnb  = (const float*)d_in[10];
  const float* bnm  = (const float*)d_in[11];
  const float* bnv  = (const float*)d_in[12];
  const float* p_w  = (const float*)d_in[13];
  const float* p_b  = (const float*)d_in[14];
  float* out = (float*)d_out;

  float* ws = (float*)d_ws;
  // f32-slot layout, no aliasing (~13.1 MB):
  bf16_t* Qb   = (bf16_t*)(ws);             // [0, 819200)       1,638,400 u16
  bf16_t* Kp   = (bf16_t*)(ws + 819200);    // [819200, 1024000)   409,600 u16
  bf16_t* Vp   = (bf16_t*)(ws + 1024000);   // [1024000, 1433600)  819,200 u16
  float*  Lsum = ws + 1433600;              // [1433600, 1638400)  204,800 f32
  bf16_t* Pb   = (bf16_t*)(ws + 1638400);   // [1638400, 3276800) 4 slices

  const float sl = 0.25f * LOG2E;  // SCALE * log2(e) folded into Q

  // 1. fused q + sr->k->v directly from f32 inputs (prep_all eliminated)
  mgemm_qsrkv<<<dim3(250, NBATCH), dim3(256), 0, stream>>>(
      x, q_w, k_w, v_w, sr_w, q_b, sr_b, k_b, v_b, bng, bnb, bnm, bnv,
      (unsigned short*)Qb, (unsigned short*)Kp, (unsigned short*)Vp, sl);

  // 2. attention partials (kv-split = 2, pipelined, natural VGPR allocation)
  attn_split<<<dim3(NQ / 128, HEADS, 4), dim3(256), 0, stream>>>(
      Qb, Kp, Vp, (unsigned short*)Pb, Lsum);

  // 3. combine + scramble + proj -> f32 chan-major final output (B,128,80,80)
  proj_comb<<<dim3(200, NBATCH), dim3(256), 0, stream>>>(
      (const unsigned short*)Pb, Lsum, p_w, p_b, out);
}

// Round 2
// 155.155 us; speedup vs baseline: 1.0221x; 1.0221x over previous
//
#include <hip/hip_runtime.h>
#include <hip/hip_bf16.h>
#include <cmath>

#define DIM 128
#define HEADS 8
#define NBATCH 2
#define NQ 6400   /* 80*80 */
#define NKV 1600  /* 40*40 */
#define NC 50     /* kv chunks of 32 */
#define BN_EPS 1e-5f
#define LOG2E 1.4426950408889634f

typedef __bf16 bf16_t;
typedef __attribute__((ext_vector_type(8))) __bf16 bf16x8;
typedef __attribute__((ext_vector_type(16))) float f32x16;

union BF8U { bf16x8 v; unsigned u[4]; };

// pack two f32 -> packed bf16 (a->lo, b->hi); lowers to v_cvt_pk_bf16_f32 (RNE)
__device__ inline unsigned packbf2(float a, float b) {
  union { __hip_bfloat162 v; unsigned u; } r;
  r.v = __float22bfloat162_rn(make_float2(a, b));
  return r.u;
}

__device__ inline unsigned short f2bf(float v) {
  unsigned u = __float_as_uint(v);
  return (unsigned short)((u + 0x7FFFu + ((u >> 16) & 1u)) >> 16);
}

// ---------------------------------------------------------------------------
// Fused q + (sr -> bn -> relu -> k -> v) GEMMs reading f32 x / f32 weights
// directly. Round-2 fix vs round-1: A-operands are staged COOPERATIVELY into
// LDS once per block (coalesced f32 loads + packed bf16 LDS writes), instead
// of per-lane scalar gathers redundantly repeated by all 4 waves. B-operands
// are contiguous-row float4 pairs (qw/kw/vw rows of 128; srw rows of 512 in
// original im2col (c,ky,kx) order -> contiguous).
// blocks [0,50): sr->k->v (stages 32x512 X4 tile). blocks [50,250): q tile.
// Math is bit-identical to the round-0 multi-kernel pipeline.
// ---------------------------------------------------------------------------
__global__ __launch_bounds__(256) void mgemm_qsrkv(
    const float* __restrict__ x,
    const float* __restrict__ qw, const float* __restrict__ kw,
    const float* __restrict__ vw, const float* __restrict__ srw,
    const float* __restrict__ q_b, const float* __restrict__ sr_b,
    const float* __restrict__ k_b, const float* __restrict__ v_b,
    const float* __restrict__ bng, const float* __restrict__ bnb,
    const float* __restrict__ bnm, const float* __restrict__ bnv,
    unsigned short* __restrict__ Qb,
    unsigned short* __restrict__ Kp, unsigned short* __restrict__ Vp,
    float sl)
{
  __shared__ __align__(16) unsigned short xs4[32][520]; // sr A tile (im2col)
  __shared__ __align__(16) unsigned short xs[32][136];  // relu out / q A tile
  int t = threadIdx.x;
  int ln = t & 31, hf = (t >> 5) & 1, wid = t >> 6;
  int b = blockIdx.y;
  int o = wid * 32 + ln;

  if (blockIdx.x < 50) {             // ---- sr -> k -> v part ----
    int cid = blockIdx.x;
    int s0 = cid * 32;

    // Stage X4 tile: token tx, values (c,ky,kx) in im2col order c*4+ky*2+kx.
    {
      int tx = t & 31, g = t >> 5;
      int s = s0 + tx;
      int i = s / 40, j = s % 40;
      const float* xb = x + (size_t)b * DIM * NQ;
#pragma unroll
      for (int u = 0; u < 32; ++u) {
        int idx2 = g * 32 + u;       // c*2 + ky
        int c = idx2 >> 1, ky = idx2 & 1;
        const float* src = xb + (size_t)c * NQ + (2 * i + ky) * 80 + 2 * j;
        float2 vv = *(const float2*)src;             // kx = 0,1 contiguous
        *(unsigned*)&xs4[tx][c * 4 + ky * 2] = packbf2(vv.x, vv.y);
      }
    }
    __syncthreads();

    // sr GEMM: K = 512 off the LDS tile; B rows of srw are contiguous f32.
    const unsigned short* arow = &xs4[ln][hf * 8];
    const float* wrow = srw + (size_t)o * 512;
    f32x16 acc = {};
#pragma unroll 8
    for (int c0 = 0; c0 < 512; c0 += 16) {
      int cb = c0 + hf * 8;
      bf16x8 af = *(const bf16x8*)&arow[c0];
      BF8U bf;
      float4 w0 = *(const float4*)(wrow + cb);
      float4 w1 = *(const float4*)(wrow + cb + 4);
      bf.u[0] = packbf2(w0.x, w0.y); bf.u[1] = packbf2(w0.z, w0.w);
      bf.u[2] = packbf2(w1.x, w1.y); bf.u[3] = packbf2(w1.z, w1.w);
      acc = __builtin_amdgcn_mfma_f32_32x32x16_bf16(af, bf.v, acc, 0, 0, 0);
    }
    float bv = sr_b[o];
    float inv = bng[o] / sqrtf(bnv[o] + BN_EPS);
    float b2 = bnb[o] - bnm[o] * inv;
#pragma unroll
    for (int g = 0; g < 4; ++g)
#pragma unroll
      for (int jj = 0; jj < 4; ++jj) {
        int sr = 8 * g + 4 * hf + jj;
        xs[sr][o] = f2bf(fmaxf((acc[4 * g + jj] + bv) * inv + b2, 0.f));
      }
    __syncthreads();

    // k + v GEMMs (C=128) off the LDS tile, f32 weights cast inline
    const unsigned short* ar2 = &xs[ln][hf * 8];
    const float* kwrow = kw + (size_t)o * DIM;
    const float* vwrow = vw + (size_t)o * DIM;
    f32x16 ka = {}, va = {};
#pragma unroll
    for (int c0 = 0; c0 < 128; c0 += 16) {
      int cb = c0 + hf * 8;
      bf16x8 af = *(const bf16x8*)&ar2[c0];
      BF8U kb, vb;
      float4 k0 = *(const float4*)(kwrow + cb);
      float4 k1 = *(const float4*)(kwrow + cb + 4);
      float4 v0 = *(const float4*)(vwrow + cb);
      float4 v1 = *(const float4*)(vwrow + cb + 4);
      kb.u[0] = packbf2(k0.x, k0.y); kb.u[1] = packbf2(k0.z, k0.w);
      kb.u[2] = packbf2(k1.x, k1.y); kb.u[3] = packbf2(k1.z, k1.w);
      vb.u[0] = packbf2(v0.x, v0.y); vb.u[1] = packbf2(v0.z, v0.w);
      vb.u[2] = packbf2(v1.x, v1.y); vb.u[3] = packbf2(v1.z, v1.w);
      ka = __builtin_amdgcn_mfma_f32_32x32x16_bf16(af, kb.v, ka, 0, 0, 0);
      va = __builtin_amdgcn_mfma_f32_32x32x16_bf16(af, vb.v, va, 0, 0, 0);
    }
    int hloc = o >> 4, d = o & 15;
    {
      float kb2 = k_b[o];
      size_t CB = (((size_t)b * HEADS + hloc) * NC + cid) * 512;
#pragma unroll
      for (int g = 0; g < 4; ++g)
#pragma unroll
        for (int jj = 0; jj < 4; ++jj) {
          int sl2 = 8 * g + 4 * hf + jj;
          Kp[CB + sl2 * 16 + d] = f2bf(ka[4 * g + jj] + kb2);
        }
    }
    {
      float vb2 = v_b[o];
      size_t CB = (((size_t)b * HEADS + hloc) * NC + cid) * 1024;
      uint4 w0, w1;
      w0.x = packbf2(va[0] + vb2, va[1] + vb2);
      w0.y = packbf2(va[2] + vb2, va[3] + vb2);
      w0.z = packbf2(va[4] + vb2, va[5] + vb2);
      w0.w = packbf2(va[6] + vb2, va[7] + vb2);
      w1.x = packbf2(va[8] + vb2, va[9] + vb2);
      w1.y = packbf2(va[10] + vb2, va[11] + vb2);
      w1.z = packbf2(va[12] + vb2, va[13] + vb2);
      w1.w = packbf2(va[14] + vb2, va[15] + vb2);
      *(uint4*)&Vp[CB + d * 16 + hf * 8] = w0;       // va block
      *(uint4*)&Vp[CB + 512 + d * 16 + hf * 8] = w1; // vb block
    }
    // Vp lane-16 (denominator) rows for this (b, chunk), all 8 heads
    {
      int hh = t >> 5, pos = t & 31;
      size_t addr = (((size_t)b * HEADS + hh) * NC + cid) * 1024 + 256 +
                    ((pos & 16) ? 512 : 0) + (pos & 15);
      Vp[addr] = 0x3F80;               // 1.0 bf16
    }
  } else {                           // ---- q part (C = 128) ----
    int s0 = (blockIdx.x - 50) * 32;

    // Stage 32-token x 128-channel bf16 tile, token-major (coalesced reads).
    {
      int tx = t & 31, cg = t >> 5;
      const float* xb = x + (size_t)b * DIM * NQ + s0 + tx;
#pragma unroll
      for (int it = 0; it < 8; ++it) {
        int c = 2 * cg + 16 * it;
        float a0 = xb[(size_t)c * NQ];
        float a1 = xb[(size_t)(c + 1) * NQ];
        *(unsigned*)&xs[tx][c] = packbf2(a0, a1);
      }
    }
    __syncthreads();

    const unsigned short* arow = &xs[ln][hf * 8];
    const float* qwrow = qw + (size_t)o * DIM;
    f32x16 acc = {};
#pragma unroll
    for (int c0 = 0; c0 < 128; c0 += 16) {
      int cb = c0 + hf * 8;
      bf16x8 af = *(const bf16x8*)&arow[c0];
      BF8U bf;
      float4 b0 = *(const float4*)(qwrow + cb);
      float4 b1 = *(const float4*)(qwrow + cb + 4);
      bf.u[0] = packbf2(b0.x, b0.y); bf.u[1] = packbf2(b0.z, b0.w);
      bf.u[2] = packbf2(b1.x, b1.y); bf.u[3] = packbf2(b1.z, b1.w);
      acc = __builtin_amdgcn_mfma_f32_32x32x16_bf16(af, bf.v, acc, 0, 0, 0);
    }
    float bv = q_b[o];
#pragma unroll
    for (int g = 0; g < 4; ++g)
#pragma unroll
      for (int jj = 0; jj < 4; ++jj) {
        int sq = s0 + 8 * g + 4 * hf + jj;
        Qb[((size_t)b * NQ + sq) * DIM + o] = f2bf((acc[4 * g + jj] + bv) * sl);
      }
  }
}

// ---------------------------------------------------------------------------
// MFMA attention, software-pipelined (unchanged). kv-split=2, fragment-major
// K/V, 2-deep prefetch, S one chunk ahead, dual accumulators. Natural VGPR
// allocation (no min-waves arg). grid (50, 8, 4): z = b + 2*half. block 256.
// ---------------------------------------------------------------------------
__global__ __launch_bounds__(256) void attn_split(
    const bf16_t* __restrict__ Qb, const bf16_t* __restrict__ Kp,
    const bf16_t* __restrict__ Vp, unsigned short* __restrict__ Pb,
    float* __restrict__ Lsum)
{
  const int t = threadIdx.x;
  const int ln = t & 31, hf = (t >> 5) & 1, wid = t >> 6;
  const int h = blockIdx.y;
  const int b = blockIdx.z & 1, half = blockIdx.z >> 1;
  const int q0 = blockIdx.x * 128 + wid * 32;

  bf16x8 qf = *(const bf16x8*)&Qb[((size_t)b * NQ + q0 + ln) * DIM + h * 16 + hf * 8];
  const int bh = b * HEADS + h;
  const bf16_t* kc = &Kp[((size_t)bh * NC + half * 25) * 512 + ln * 16 + hf * 8];
  const bf16_t* vc = &Vp[((size_t)bh * NC + half * 25) * 1024 + ln * 16 + hf * 8];

  f32x16 acc0 = {}, acc1 = {};
  const f32x16 zero = {};

  bf16x8 kf0 = *(const bf16x8*)kc;
  bf16x8 va0 = *(const bf16x8*)vc;
  bf16x8 vb0 = *(const bf16x8*)(vc + 512);
  bf16x8 kf1 = *(const bf16x8*)(kc + 512);
  bf16x8 va1 = *(const bf16x8*)(vc + 1024);
  bf16x8 vb1 = *(const bf16x8*)(vc + 1536);

  f32x16 S0 = __builtin_amdgcn_mfma_f32_32x32x16_bf16(kf0, qf, zero, 0, 0, 0);

  for (int c = 0; c < 25; ++c) {
    int cn = (c + 2 < 25) ? c + 2 : 24;    // 2-deep prefetch (clamped)
    bf16x8 kf2 = *(const bf16x8*)(kc + (size_t)cn * 512);
    bf16x8 va2 = *(const bf16x8*)(vc + (size_t)cn * 1024);
    bf16x8 vb2 = *(const bf16x8*)(vc + (size_t)cn * 1024 + 512);

    f32x16 S1 = __builtin_amdgcn_mfma_f32_32x32x16_bf16(kf1, qf, zero, 0, 0, 0);

    BF8U f0, f1;
#pragma unroll
    for (int i = 0; i < 4; ++i) {
      f0.u[i] = packbf2(__builtin_amdgcn_exp2f(S0[2 * i]),
                        __builtin_amdgcn_exp2f(S0[2 * i + 1]));
      f1.u[i] = packbf2(__builtin_amdgcn_exp2f(S0[8 + 2 * i]),
                        __builtin_amdgcn_exp2f(S0[9 + 2 * i]));
    }

    acc0 = __builtin_amdgcn_mfma_f32_32x32x16_bf16(va0, f0.v, acc0, 0, 0, 0);
    acc1 = __builtin_amdgcn_mfma_f32_32x32x16_bf16(vb0, f1.v, acc1, 0, 0, 0);

    S0 = S1;
    kf0 = kf1; va0 = va1; vb0 = vb1;
    kf1 = kf2; va1 = va2; vb1 = vb2;
  }

  f32x16 acc;
#pragma unroll
  for (int i = 0; i < 16; ++i) acc[i] = acc0[i] + acc1[i];

  // acc: col q = ln, row d = (r&3)+8*(r>>2)+4*hf. Row16 (denom) = acc[8]@hf0.
  unsigned short* prow =
      &Pb[(size_t)(half * 2 + b) * (NQ * DIM) + (size_t)(q0 + ln) * DIM + h * 16 + 4 * hf];
  uint2 w0, w1;
  w0.x = packbf2(acc[0], acc[1]); w0.y = packbf2(acc[2], acc[3]);
  w1.x = packbf2(acc[4], acc[5]); w1.y = packbf2(acc[6], acc[7]);
  *(uint2*)&prow[0] = w0;
  *(uint2*)&prow[8] = w1;
  if (!hf)
    Lsum[(size_t)(half * 2 + b) * (HEADS * NQ) + (size_t)h * NQ + q0 + ln] = acc[8];
}

// ---------------------------------------------------------------------------
// proj_comb: fused combine (2 halves) + reference scramble + proj GEMM.
// proj weights read as f32 directly (inline bf16 cast). grid (200,2), blk 256.
// ---------------------------------------------------------------------------
__global__ __launch_bounds__(256) void proj_comb(
    const unsigned short* __restrict__ Pb, const float* __restrict__ Lsum,
    const float* __restrict__ pw, const float* __restrict__ p_b,
    float* __restrict__ Out)
{
  __shared__ __align__(16) unsigned short As[32][136];
  int t = threadIdx.x;
  int b = blockIdx.y;
  int s0 = blockIdx.x * 32;

  {
    int tx = t & 31, cg = t >> 5;          // lane sweeps s (coalesced in f)
#pragma unroll
    for (int it = 0; it < 16; ++it) {
      int c = cg * 16 + it;
      int f = c * NQ + s0 + tx;            // flat att index = n*128 + h*16+d
      int n = f >> 7, hh = (f >> 4) & 7;
      float p0 = __uint_as_float((unsigned)Pb[(size_t)b * (NQ * DIM) + f] << 16);
      float p1 = __uint_as_float((unsigned)Pb[(size_t)(2 + b) * (NQ * DIM) + f] << 16);
      float L = Lsum[(size_t)b * (HEADS * NQ) + (size_t)hh * NQ + n] +
                Lsum[(size_t)(2 + b) * (HEADS * NQ) + (size_t)hh * NQ + n];
      As[tx][c] = f2bf((p0 + p1) / L);
    }
  }
  __syncthreads();

  int ln = t & 31, hf = (t >> 5) & 1, wid = t >> 6;
  int o = wid * 32 + ln;
  const float* brow = pw + (size_t)o * DIM;
  const unsigned short* arow = &As[ln][hf * 8];
  f32x16 acc = {};
#pragma unroll
  for (int c0 = 0; c0 < 128; c0 += 16) {
    int cb = c0 + hf * 8;
    bf16x8 af = *(const bf16x8*)&arow[c0];
    BF8U bf;
    float4 b0 = *(const float4*)(brow + cb);
    float4 b1 = *(const float4*)(brow + cb + 4);
    bf.u[0] = packbf2(b0.x, b0.y); bf.u[1] = packbf2(b0.z, b0.w);
    bf.u[2] = packbf2(b1.x, b1.y); bf.u[3] = packbf2(b1.z, b1.w);
    acc = __builtin_amdgcn_mfma_f32_32x32x16_bf16(af, bf.v, acc, 0, 0, 0);
  }
  float bv = p_b[o];
  float* obase = &Out[((size_t)b * DIM + o) * NQ + s0 + 4 * hf];
#pragma unroll
  for (int g = 0; g < 4; ++g) {
    float4 r;
    r.x = acc[4 * g + 0] + bv; r.y = acc[4 * g + 1] + bv;
    r.z = acc[4 * g + 2] + bv; r.w = acc[4 * g + 3] + bv;
    *(float4*)&obase[8 * g] = r;
  }
}

// ---------------------------------------------------------------------------
extern "C" void kernel_launch(void* const* d_in, const int* in_sizes, int n_in,
                              void* d_out, int out_size, void* d_ws, size_t ws_size,
                              hipStream_t stream)
{
  const float* x    = (const float*)d_in[0];
  const float* q_w  = (const float*)d_in[1];
  const float* q_b  = (const float*)d_in[2];
  const float* k_w  = (const float*)d_in[3];
  const float* k_b  = (const float*)d_in[4];
  const float* v_w  = (const float*)d_in[5];
  const float* v_b  = (const float*)d_in[6];
  const float* sr_w = (const float*)d_in[7];
  const float* sr_b = (const float*)d_in[8];
  const float* bng  = (const float*)d_in[9];
  const float* bnb  = (const float*)d_in[10];
  const float* bnm  = (const float*)d_in[11];
  const float* bnv  = (const float*)d_in[12];
  const float* p_w  = (const float*)d_in[13];
  const float* p_b  = (const float*)d_in[14];
  float* out = (float*)d_out;

  float* ws = (float*)d_ws;
  // f32-slot layout, no aliasing (~13.1 MB):
  bf16_t* Qb   = (bf16_t*)(ws);             // [0, 819200)       1,638,400 u16
  bf16_t* Kp   = (bf16_t*)(ws + 819200);    // [819200, 1024000)   409,600 u16
  bf16_t* Vp   = (bf16_t*)(ws + 1024000);   // [1024000, 1433600)  819,200 u16
  float*  Lsum = ws + 1433600;              // [1433600, 1638400)  204,800 f32
  bf16_t* Pb   = (bf16_t*)(ws + 1638400);   // [1638400, 3276800) 4 slices

  const float sl = 0.25f * LOG2E;  // SCALE * log2(e) folded into Q

  // 1. fused q + sr->k->v directly from f32 inputs (LDS-staged A operands)
  mgemm_qsrkv<<<dim3(250, NBATCH), dim3(256), 0, stream>>>(
      x, q_w, k_w, v_w, sr_w, q_b, sr_b, k_b, v_b, bng, bnb, bnm, bnv,
      (unsigned short*)Qb, (unsigned short*)Kp, (unsigned short*)Vp, sl);

  // 2. attention partials (kv-split = 2, pipelined, natural VGPR allocation)
  attn_split<<<dim3(NQ / 128, HEADS, 4), dim3(256), 0, stream>>>(
      Qb, Kp, Vp, (unsigned short*)Pb, Lsum);

  // 3. combine + scramble + proj -> f32 chan-major final output (B,128,80,80)
  proj_comb<<<dim3(200, NBATCH), dim3(256), 0, stream>>>(
      (const unsigned short*)Pb, Lsum, p_w, p_b, out);
}

// Round 3
// 145.073 us; speedup vs baseline: 1.0931x; 1.0695x over previous
//
#include <hip/hip_runtime.h>
#include <hip/hip_bf16.h>
#include <cmath>

#define DIM 128
#define HEADS 8
#define NBATCH 2
#define NQ 6400   /* 80*80 */
#define NKV 1600  /* 40*40 */
#define NC 50     /* kv chunks of 32 */
#define BN_EPS 1e-5f
#define LOG2E 1.4426950408889634f

typedef __bf16 bf16_t;
typedef __attribute__((ext_vector_type(8))) __bf16 bf16x8;
typedef __attribute__((ext_vector_type(16))) float f32x16;

union BF8U { bf16x8 v; unsigned u[4]; };

// pack two f32 -> packed bf16 (a->lo, b->hi); lowers to v_cvt_pk_bf16_f32 (RNE)
__device__ inline unsigned packbf2(float a, float b) {
  union { __hip_bfloat162 v; unsigned u; } r;
  r.v = __float22bfloat162_rn(make_float2(a, b));
  return r.u;
}

__device__ inline unsigned short f2bf(float v) {
  unsigned u = __float_as_uint(v);
  return (unsigned short)((u + 0x7FFFu + ((u >> 16) & 1u)) >> 16);
}

// ---------------------------------------------------------------------------
// wcast: one-time f32 -> bf16 weight cast (q|k|v|proj|sr -> Wb, round-0
// layout). 131072 elems, fully coalesced float4 loads. 128 blocks.
// Removes the redundant per-block inline weight conversion that made the
// round-1/2 fused GEMMs slower than the round-0 split (strided f32 gathers
// on the MFMA critical path, repeated by every block).
// ---------------------------------------------------------------------------
__global__ __launch_bounds__(256) void wcast(
    const float* __restrict__ qw, const float* __restrict__ kw,
    const float* __restrict__ vw, const float* __restrict__ pw,
    const float* __restrict__ srw, unsigned short* __restrict__ Wb)
{
  int e4 = (blockIdx.x * 256 + threadIdx.x) * 4;   // 0..131068, step 4
  const float* src; int idx;
  if (e4 < 16384)      { src = qw;  idx = e4; }
  else if (e4 < 32768) { src = kw;  idx = e4 - 16384; }
  else if (e4 < 49152) { src = vw;  idx = e4 - 32768; }
  else if (e4 < 65536) { src = pw;  idx = e4 - 49152; }
  else                 { src = srw; idx = e4 - 65536; }
  float4 v = *(const float4*)(src + idx);
  uint2 wv;
  wv.x = packbf2(v.x, v.y);
  wv.y = packbf2(v.z, v.w);
  *(uint2*)&Wb[e4] = wv;
}

// ---------------------------------------------------------------------------
// Fused q + (sr -> bn -> relu -> k -> v) GEMMs. A-operands staged from f32 x
// into LDS per block (transpose/im2col fused, no global round trip);
// B-operands are bf16 rows of Wb (round-0 pattern, L1/L2-resident 16B/lane).
// blocks [0,50): sr->k->v (stages 32x512 X4 tile). blocks [50,250): q tile.
// Math bit-identical to the round-0 multi-kernel pipeline.
// ---------------------------------------------------------------------------
__global__ __launch_bounds__(256) void mgemm_qsrkv(
    const float* __restrict__ x, const bf16_t* __restrict__ Wb,
    const float* __restrict__ q_b, const float* __restrict__ sr_b,
    const float* __restrict__ k_b, const float* __restrict__ v_b,
    const float* __restrict__ bng, const float* __restrict__ bnb,
    const float* __restrict__ bnm, const float* __restrict__ bnv,
    unsigned short* __restrict__ Qb,
    unsigned short* __restrict__ Kp, unsigned short* __restrict__ Vp,
    float sl)
{
  __shared__ __align__(16) unsigned short xs4[32][520]; // sr A tile (im2col)
  __shared__ __align__(16) unsigned short xs[32][136];  // relu out / q A tile
  int t = threadIdx.x;
  int ln = t & 31, hf = (t >> 5) & 1, wid = t >> 6;
  int b = blockIdx.y;
  int o = wid * 32 + ln;

  if (blockIdx.x < 50) {             // ---- sr -> k -> v part ----
    int cid = blockIdx.x;
    int s0 = cid * 32;

    // Stage X4 tile: token tx, values (c,ky,kx) in im2col order c*4+ky*2+kx.
    {
      int tx = t & 31, g = t >> 5;
      int s = s0 + tx;
      int i = s / 40, j = s % 40;
      const float* xb = x + (size_t)b * DIM * NQ;
#pragma unroll
      for (int u = 0; u < 32; ++u) {
        int idx2 = g * 32 + u;       // c*2 + ky
        int c = idx2 >> 1, ky = idx2 & 1;
        const float* src = xb + (size_t)c * NQ + (2 * i + ky) * 80 + 2 * j;
        float2 vv = *(const float2*)src;             // kx = 0,1 contiguous
        *(unsigned*)&xs4[tx][c * 4 + ky * 2] = packbf2(vv.x, vv.y);
      }
    }
    __syncthreads();

    // sr GEMM: K = 512 off the LDS tile; B rows from Wb (bf16).
    const unsigned short* arow = &xs4[ln][hf * 8];
    const bf16_t* brow = &Wb[65536 + (size_t)o * 512 + hf * 8];
    f32x16 acc = {};
#pragma unroll 8
    for (int c0 = 0; c0 < 512; c0 += 16) {
      bf16x8 af = *(const bf16x8*)&arow[c0];
      bf16x8 bf = *(const bf16x8*)&brow[c0];
      acc = __builtin_amdgcn_mfma_f32_32x32x16_bf16(af, bf, acc, 0, 0, 0);
    }
    float bv = sr_b[o];
    float inv = bng[o] / sqrtf(bnv[o] + BN_EPS);
    float b2 = bnb[o] - bnm[o] * inv;
#pragma unroll
    for (int g = 0; g < 4; ++g)
#pragma unroll
      for (int jj = 0; jj < 4; ++jj) {
        int sr = 8 * g + 4 * hf + jj;
        xs[sr][o] = f2bf(fmaxf((acc[4 * g + jj] + bv) * inv + b2, 0.f));
      }
    __syncthreads();

    // k + v GEMMs (C=128) off the LDS tile, bf16 weight rows
    const unsigned short* ar2 = &xs[ln][hf * 8];
    const bf16_t* kbrow = &Wb[16384 + (size_t)o * DIM + hf * 8];
    const bf16_t* vbrow = &Wb[32768 + (size_t)o * DIM + hf * 8];
    f32x16 ka = {}, va = {};
#pragma unroll
    for (int c0 = 0; c0 < 128; c0 += 16) {
      bf16x8 af = *(const bf16x8*)&ar2[c0];
      bf16x8 kb = *(const bf16x8*)&kbrow[c0];
      bf16x8 vb = *(const bf16x8*)&vbrow[c0];
      ka = __builtin_amdgcn_mfma_f32_32x32x16_bf16(af, kb, ka, 0, 0, 0);
      va = __builtin_amdgcn_mfma_f32_32x32x16_bf16(af, vb, va, 0, 0, 0);
    }
    int hloc = o >> 4, d = o & 15;
    {
      float kb2 = k_b[o];
      size_t CB = (((size_t)b * HEADS + hloc) * NC + cid) * 512;
#pragma unroll
      for (int g = 0; g < 4; ++g)
#pragma unroll
        for (int jj = 0; jj < 4; ++jj) {
          int sl2 = 8 * g + 4 * hf + jj;
          Kp[CB + sl2 * 16 + d] = f2bf(ka[4 * g + jj] + kb2);
        }
    }
    {
      float vb2 = v_b[o];
      size_t CB = (((size_t)b * HEADS + hloc) * NC + cid) * 1024;
      uint4 w0, w1;
      w0.x = packbf2(va[0] + vb2, va[1] + vb2);
      w0.y = packbf2(va[2] + vb2, va[3] + vb2);
      w0.z = packbf2(va[4] + vb2, va[5] + vb2);
      w0.w = packbf2(va[6] + vb2, va[7] + vb2);
      w1.x = packbf2(va[8] + vb2, va[9] + vb2);
      w1.y = packbf2(va[10] + vb2, va[11] + vb2);
      w1.z = packbf2(va[12] + vb2, va[13] + vb2);
      w1.w = packbf2(va[14] + vb2, va[15] + vb2);
      *(uint4*)&Vp[CB + d * 16 + hf * 8] = w0;       // va block
      *(uint4*)&Vp[CB + 512 + d * 16 + hf * 8] = w1; // vb block
    }
    // Vp lane-16 (denominator) rows for this (b, chunk), all 8 heads
    {
      int hh = t >> 5, pos = t & 31;
      size_t addr = (((size_t)b * HEADS + hh) * NC + cid) * 1024 + 256 +
                    ((pos & 16) ? 512 : 0) + (pos & 15);
      Vp[addr] = 0x3F80;               // 1.0 bf16
    }
  } else {                           // ---- q part (C = 128) ----
    int s0 = (blockIdx.x - 50) * 32;

    // Stage 32-token x 128-channel bf16 tile, token-major (coalesced reads).
    {
      int tx = t & 31, cg = t >> 5;
      const float* xb = x + (size_t)b * DIM * NQ + s0 + tx;
#pragma unroll
      for (int it = 0; it < 8; ++it) {
        int c = 2 * cg + 16 * it;
        float a0 = xb[(size_t)c * NQ];
        float a1 = xb[(size_t)(c + 1) * NQ];
        *(unsigned*)&xs[tx][c] = packbf2(a0, a1);
      }
    }
    __syncthreads();

    const unsigned short* arow = &xs[ln][hf * 8];
    const bf16_t* brow = &Wb[(size_t)o * DIM + hf * 8];
    f32x16 acc = {};
#pragma unroll
    for (int c0 = 0; c0 < 128; c0 += 16) {
      bf16x8 af = *(const bf16x8*)&arow[c0];
      bf16x8 bf = *(const bf16x8*)&brow[c0];
      acc = __builtin_amdgcn_mfma_f32_32x32x16_bf16(af, bf, acc, 0, 0, 0);
    }
    float bv = q_b[o];
#pragma unroll
    for (int g = 0; g < 4; ++g)
#pragma unroll
      for (int jj = 0; jj < 4; ++jj) {
        int sq = s0 + 8 * g + 4 * hf + jj;
        Qb[((size_t)b * NQ + sq) * DIM + o] = f2bf((acc[4 * g + jj] + bv) * sl);
      }
  }
}

// ---------------------------------------------------------------------------
// MFMA attention, 2 q-tiles per wave (round-3). K/V fragments are SHARED by
// both tiles (half the L2 gathers per exp) and the two independent
// S->exp->PV chains give in-wave ILP that the 30%-occupancy single-chain
// version lacked (MfmaUtil was 14%, VALUBusy 55% = stall-bound).
// kv-split=2, fragment-major K/V, 2-deep prefetch, dual accumulators/tile.
// grid (25, 8, 4): z = b + 2*half. block 256.
// ---------------------------------------------------------------------------
__global__ __launch_bounds__(256) void attn_split(
    const bf16_t* __restrict__ Qb, const bf16_t* __restrict__ Kp,
    const bf16_t* __restrict__ Vp, unsigned short* __restrict__ Pb,
    float* __restrict__ Lsum)
{
  const int t = threadIdx.x;
  const int ln = t & 31, hf = (t >> 5) & 1, wid = t >> 6;
  const int h = blockIdx.y;
  const int b = blockIdx.z & 1, half = blockIdx.z >> 1;
  const int q0 = blockIdx.x * 256 + wid * 32;   // tile A
  const int q1 = q0 + 128;                      // tile B

  bf16x8 qfA = *(const bf16x8*)&Qb[((size_t)b * NQ + q0 + ln) * DIM + h * 16 + hf * 8];
  bf16x8 qfB = *(const bf16x8*)&Qb[((size_t)b * NQ + q1 + ln) * DIM + h * 16 + hf * 8];
  const int bh = b * HEADS + h;
  const bf16_t* kc = &Kp[((size_t)bh * NC + half * 25) * 512 + ln * 16 + hf * 8];
  const bf16_t* vc = &Vp[((size_t)bh * NC + half * 25) * 1024 + ln * 16 + hf * 8];

  f32x16 aA0 = {}, aA1 = {}, aB0 = {}, aB1 = {};
  const f32x16 zero = {};

  bf16x8 kf0 = *(const bf16x8*)kc;
  bf16x8 va0 = *(const bf16x8*)vc;
  bf16x8 vb0 = *(const bf16x8*)(vc + 512);
  bf16x8 kf1 = *(const bf16x8*)(kc + 512);
  bf16x8 va1 = *(const bf16x8*)(vc + 1024);
  bf16x8 vb1 = *(const bf16x8*)(vc + 1536);

  f32x16 S0a = __builtin_amdgcn_mfma_f32_32x32x16_bf16(kf0, qfA, zero, 0, 0, 0);
  f32x16 S0b = __builtin_amdgcn_mfma_f32_32x32x16_bf16(kf0, qfB, zero, 0, 0, 0);

  for (int c = 0; c < 25; ++c) {
    int cn = (c + 2 < 25) ? c + 2 : 24;    // 2-deep prefetch (clamped)
    bf16x8 kf2 = *(const bf16x8*)(kc + (size_t)cn * 512);
    bf16x8 va2 = *(const bf16x8*)(vc + (size_t)cn * 1024);
    bf16x8 vb2 = *(const bf16x8*)(vc + (size_t)cn * 1024 + 512);

    f32x16 S1a = __builtin_amdgcn_mfma_f32_32x32x16_bf16(kf1, qfA, zero, 0, 0, 0);
    f32x16 S1b = __builtin_amdgcn_mfma_f32_32x32x16_bf16(kf1, qfB, zero, 0, 0, 0);

    {
      BF8U f0, f1;
#pragma unroll
      for (int i = 0; i < 4; ++i) {
        f0.u[i] = packbf2(__builtin_amdgcn_exp2f(S0a[2 * i]),
                          __builtin_amdgcn_exp2f(S0a[2 * i + 1]));
        f1.u[i] = packbf2(__builtin_amdgcn_exp2f(S0a[8 + 2 * i]),
                          __builtin_amdgcn_exp2f(S0a[9 + 2 * i]));
      }
      aA0 = __builtin_amdgcn_mfma_f32_32x32x16_bf16(va0, f0.v, aA0, 0, 0, 0);
      aA1 = __builtin_amdgcn_mfma_f32_32x32x16_bf16(vb0, f1.v, aA1, 0, 0, 0);
    }
    {
      BF8U f0, f1;
#pragma unroll
      for (int i = 0; i < 4; ++i) {
        f0.u[i] = packbf2(__builtin_amdgcn_exp2f(S0b[2 * i]),
                          __builtin_amdgcn_exp2f(S0b[2 * i + 1]));
        f1.u[i] = packbf2(__builtin_amdgcn_exp2f(S0b[8 + 2 * i]),
                          __builtin_amdgcn_exp2f(S0b[9 + 2 * i]));
      }
      aB0 = __builtin_amdgcn_mfma_f32_32x32x16_bf16(va0, f0.v, aB0, 0, 0, 0);
      aB1 = __builtin_amdgcn_mfma_f32_32x32x16_bf16(vb0, f1.v, aB1, 0, 0, 0);
    }

    S0a = S1a; S0b = S1b;
    kf0 = kf1; va0 = va1; vb0 = vb1;
    kf1 = kf2; va1 = va2; vb1 = vb2;
  }

  f32x16 accA, accB;
#pragma unroll
  for (int i = 0; i < 16; ++i) { accA[i] = aA0[i] + aA1[i]; accB[i] = aB0[i] + aB1[i]; }

  // acc: col q = ln, row d = (r&3)+8*(r>>2)+4*hf. Row16 (denom) = acc[8]@hf0.
  size_t sbase = (size_t)(half * 2 + b) * (NQ * DIM);
  {
    unsigned short* prow = &Pb[sbase + (size_t)(q0 + ln) * DIM + h * 16 + 4 * hf];
    uint2 w0, w1;
    w0.x = packbf2(accA[0], accA[1]); w0.y = packbf2(accA[2], accA[3]);
    w1.x = packbf2(accA[4], accA[5]); w1.y = packbf2(accA[6], accA[7]);
    *(uint2*)&prow[0] = w0;
    *(uint2*)&prow[8] = w1;
  }
  {
    unsigned short* prow = &Pb[sbase + (size_t)(q1 + ln) * DIM + h * 16 + 4 * hf];
    uint2 w0, w1;
    w0.x = packbf2(accB[0], accB[1]); w0.y = packbf2(accB[2], accB[3]);
    w1.x = packbf2(accB[4], accB[5]); w1.y = packbf2(accB[6], accB[7]);
    *(uint2*)&prow[0] = w0;
    *(uint2*)&prow[8] = w1;
  }
  if (!hf) {
    size_t lbase = (size_t)(half * 2 + b) * (HEADS * NQ) + (size_t)h * NQ;
    Lsum[lbase + q0 + ln] = accA[8];
    Lsum[lbase + q1 + ln] = accB[8];
  }
}

// ---------------------------------------------------------------------------
// proj_comb: fused combine (2 halves) + reference scramble + proj GEMM.
// Combine loads widened to u32 (2 tokens/lane: flat-index scramble is the
// identity, so f,f+1 = adjacent tokens, same (n,hh) since d<=14 -> one Lsum
// fetch per pair). Proj weights from bf16 Wb. grid (200,2), blk 256.
// ---------------------------------------------------------------------------
__global__ __launch_bounds__(256) void proj_comb(
    const unsigned short* __restrict__ Pb, const float* __restrict__ Lsum,
    const bf16_t* __restrict__ Wb, const float* __restrict__ p_b,
    float* __restrict__ Out)
{
  __shared__ __align__(16) unsigned short As[32][136];
  int t = threadIdx.x;
  int b = blockIdx.y;
  int s0 = blockIdx.x * 32;

  {
    int tp = t & 15, cg = t >> 4;          // token pair, 16 channel groups
    const unsigned short* p0base = Pb + (size_t)b * (NQ * DIM);
    const unsigned short* p1base = Pb + (size_t)(2 + b) * (NQ * DIM);
#pragma unroll
    for (int it = 0; it < 8; ++it) {
      int c = cg * 8 + it;
      int f = c * NQ + s0 + 2 * tp;        // flat att index; even -> d<=14
      int n = f >> 7, hh = (f >> 4) & 7;
      unsigned u0 = *(const unsigned*)&p0base[f];
      unsigned u1 = *(const unsigned*)&p1base[f];
      float L = Lsum[(size_t)b * (HEADS * NQ) + (size_t)hh * NQ + n] +
                Lsum[(size_t)(2 + b) * (HEADS * NQ) + (size_t)hh * NQ + n];
      float plo = __uint_as_float(u0 << 16) + __uint_as_float(u1 << 16);
      float phi = __uint_as_float(u0 & 0xFFFF0000u) + __uint_as_float(u1 & 0xFFFF0000u);
      As[2 * tp][c]     = f2bf(plo / L);
      As[2 * tp + 1][c] = f2bf(phi / L);
    }
  }
  __syncthreads();

  int ln = t & 31, hf = (t >> 5) & 1, wid = t >> 6;
  int o = wid * 32 + ln;
  const bf16_t* brow = &Wb[49152 + (size_t)o * DIM + hf * 8];
  const unsigned short* arow = &As[ln][hf * 8];
  f32x16 acc = {};
#pragma unroll
  for (int c0 = 0; c0 < 128; c0 += 16) {
    bf16x8 af = *(const bf16x8*)&arow[c0];
    bf16x8 bf = *(const bf16x8*)&brow[c0];
    acc = __builtin_amdgcn_mfma_f32_32x32x16_bf16(af, bf, acc, 0, 0, 0);
  }
  float bv = p_b[o];
  float* obase = &Out[((size_t)b * DIM + o) * NQ + s0 + 4 * hf];
#pragma unroll
  for (int g = 0; g < 4; ++g) {
    float4 r;
    r.x = acc[4 * g + 0] + bv; r.y = acc[4 * g + 1] + bv;
    r.z = acc[4 * g + 2] + bv; r.w = acc[4 * g + 3] + bv;
    *(float4*)&obase[8 * g] = r;
  }
}

// ---------------------------------------------------------------------------
extern "C" void kernel_launch(void* const* d_in, const int* in_sizes, int n_in,
                              void* d_out, int out_size, void* d_ws, size_t ws_size,
                              hipStream_t stream)
{
  const float* x    = (const float*)d_in[0];
  const float* q_w  = (const float*)d_in[1];
  const float* q_b  = (const float*)d_in[2];
  const float* k_w  = (const float*)d_in[3];
  const float* k_b  = (const float*)d_in[4];
  const float* v_w  = (const float*)d_in[5];
  const float* v_b  = (const float*)d_in[6];
  const float* sr_w = (const float*)d_in[7];
  const float* sr_b = (const float*)d_in[8];
  const float* bng  = (const float*)d_in[9];
  const float* bnb  = (const float*)d_in[10];
  const float* bnm  = (const float*)d_in[11];
  const float* bnv  = (const float*)d_in[12];
  const float* p_w  = (const float*)d_in[13];
  const float* p_b  = (const float*)d_in[14];
  float* out = (float*)d_out;

  float* ws = (float*)d_ws;
  // f32-slot layout, no aliasing (~13.4 MB):
  bf16_t* Qb   = (bf16_t*)(ws);             // [0, 819200)       1,638,400 u16
  bf16_t* Kp   = (bf16_t*)(ws + 819200);    // [819200, 1024000)   409,600 u16
  bf16_t* Vp   = (bf16_t*)(ws + 1024000);   // [1024000, 1433600)  819,200 u16
  float*  Lsum = ws + 1433600;              // [1433600, 1638400)  204,800 f32
  bf16_t* Pb   = (bf16_t*)(ws + 1638400);   // [1638400, 3276800) 4 slices
  bf16_t* Wb   = (bf16_t*)(ws + 3276800);   // [3276800, 3342336) 131,072 u16

  const float sl = 0.25f * LOG2E;  // SCALE * log2(e) folded into Q

  // 1. one-time weight cast (tiny)
  wcast<<<dim3(128), dim3(256), 0, stream>>>(
      q_w, k_w, v_w, p_w, sr_w, (unsigned short*)Wb);

  // 2. fused q + sr->k->v from f32 x (LDS-staged A) + bf16 Wb rows
  mgemm_qsrkv<<<dim3(250, NBATCH), dim3(256), 0, stream>>>(
      x, Wb, q_b, sr_b, k_b, v_b, bng, bnb, bnm, bnv,
      (unsigned short*)Qb, (unsigned short*)Kp, (unsigned short*)Vp, sl);

  // 3. attention partials (kv-split = 2, 2 q-tiles/wave, shared K/V frags)
  attn_split<<<dim3(NQ / 256, HEADS, 4), dim3(256), 0, stream>>>(
      Qb, Kp, Vp, (unsigned short*)Pb, Lsum);

  // 4. combine + scramble + proj -> f32 chan-major final output (B,128,80,80)
  proj_comb<<<dim3(200, NBATCH), dim3(256), 0, stream>>>(
      (const unsigned short*)Pb, Lsum, Wb, p_b, out);
}

// Round 4
// 143.745 us; speedup vs baseline: 1.1032x; 1.0092x over previous
//
#include <hip/hip_runtime.h>
#include <hip/hip_bf16.h>
#include <cmath>

#define DIM 128
#define HEADS 8
#define NBATCH 2
#define NQ 6400   /* 80*80 */
#define NKV 1600  /* 40*40 */
#define NC 50     /* kv chunks of 32 */
#define NSPLIT 5  /* kv-split count */
#define CPS 10    /* chunks per split */
#define BN_EPS 1e-5f
#define LOG2E 1.4426950408889634f

typedef __bf16 bf16_t;
typedef __attribute__((ext_vector_type(8))) __bf16 bf16x8;
typedef __attribute__((ext_vector_type(16))) float f32x16;

union BF8U { bf16x8 v; unsigned u[4]; };

// pack two f32 -> packed bf16 (a->lo, b->hi); lowers to v_cvt_pk_bf16_f32 (RNE)
__device__ inline unsigned packbf2(float a, float b) {
  union { __hip_bfloat162 v; unsigned u; } r;
  r.v = __float22bfloat162_rn(make_float2(a, b));
  return r.u;
}

__device__ inline unsigned short f2bf(float v) {
  unsigned u = __float_as_uint(v);
  return (unsigned short)((u + 0x7FFFu + ((u >> 16) & 1u)) >> 16);
}

// ---------------------------------------------------------------------------
// wcast: one-time f32 -> bf16 weight cast (q|k|v|proj|sr -> Wb). 128 blocks.
// ---------------------------------------------------------------------------
__global__ __launch_bounds__(256) void wcast(
    const float* __restrict__ qw, const float* __restrict__ kw,
    const float* __restrict__ vw, const float* __restrict__ pw,
    const float* __restrict__ srw, unsigned short* __restrict__ Wb)
{
  int e4 = (blockIdx.x * 256 + threadIdx.x) * 4;   // 0..131068, step 4
  const float* src; int idx;
  if (e4 < 16384)      { src = qw;  idx = e4; }
  else if (e4 < 32768) { src = kw;  idx = e4 - 16384; }
  else if (e4 < 49152) { src = vw;  idx = e4 - 32768; }
  else if (e4 < 65536) { src = pw;  idx = e4 - 49152; }
  else                 { src = srw; idx = e4 - 65536; }
  float4 v = *(const float4*)(src + idx);
  uint2 wv;
  wv.x = packbf2(v.x, v.y);
  wv.y = packbf2(v.z, v.w);
  *(uint2*)&Wb[e4] = wv;
}

// ---------------------------------------------------------------------------
// Fused q + (sr -> bn -> relu -> k -> v) GEMMs. A-operands staged from f32 x
// into LDS per block (transpose/im2col fused); B-operands bf16 rows of Wb.
// blocks [0,50): sr->k->v. blocks [50,250): q tile. (unchanged from round 3)
// ---------------------------------------------------------------------------
__global__ __launch_bounds__(256) void mgemm_qsrkv(
    const float* __restrict__ x, const bf16_t* __restrict__ Wb,
    const float* __restrict__ q_b, const float* __restrict__ sr_b,
    const float* __restrict__ k_b, const float* __restrict__ v_b,
    const float* __restrict__ bng, const float* __restrict__ bnb,
    const float* __restrict__ bnm, const float* __restrict__ bnv,
    unsigned short* __restrict__ Qb,
    unsigned short* __restrict__ Kp, unsigned short* __restrict__ Vp,
    float sl)
{
  __shared__ __align__(16) unsigned short xs4[32][520]; // sr A tile (im2col)
  __shared__ __align__(16) unsigned short xs[32][136];  // relu out / q A tile
  int t = threadIdx.x;
  int ln = t & 31, hf = (t >> 5) & 1, wid = t >> 6;
  int b = blockIdx.y;
  int o = wid * 32 + ln;

  if (blockIdx.x < 50) {             // ---- sr -> k -> v part ----
    int cid = blockIdx.x;
    int s0 = cid * 32;

    // Stage X4 tile: token tx, values (c,ky,kx) in im2col order c*4+ky*2+kx.
    {
      int tx = t & 31, g = t >> 5;
      int s = s0 + tx;
      int i = s / 40, j = s % 40;
      const float* xb = x + (size_t)b * DIM * NQ;
#pragma unroll
      for (int u = 0; u < 32; ++u) {
        int idx2 = g * 32 + u;       // c*2 + ky
        int c = idx2 >> 1, ky = idx2 & 1;
        const float* src = xb + (size_t)c * NQ + (2 * i + ky) * 80 + 2 * j;
        float2 vv = *(const float2*)src;             // kx = 0,1 contiguous
        *(unsigned*)&xs4[tx][c * 4 + ky * 2] = packbf2(vv.x, vv.y);
      }
    }
    __syncthreads();

    // sr GEMM: K = 512 off the LDS tile; B rows from Wb (bf16).
    const unsigned short* arow = &xs4[ln][hf * 8];
    const bf16_t* brow = &Wb[65536 + (size_t)o * 512 + hf * 8];
    f32x16 acc = {};
#pragma unroll 8
    for (int c0 = 0; c0 < 512; c0 += 16) {
      bf16x8 af = *(const bf16x8*)&arow[c0];
      bf16x8 bf = *(const bf16x8*)&brow[c0];
      acc = __builtin_amdgcn_mfma_f32_32x32x16_bf16(af, bf, acc, 0, 0, 0);
    }
    float bv = sr_b[o];
    float inv = bng[o] / sqrtf(bnv[o] + BN_EPS);
    float b2 = bnb[o] - bnm[o] * inv;
#pragma unroll
    for (int g = 0; g < 4; ++g)
#pragma unroll
      for (int jj = 0; jj < 4; ++jj) {
        int sr = 8 * g + 4 * hf + jj;
        xs[sr][o] = f2bf(fmaxf((acc[4 * g + jj] + bv) * inv + b2, 0.f));
      }
    __syncthreads();

    // k + v GEMMs (C=128) off the LDS tile, bf16 weight rows
    const unsigned short* ar2 = &xs[ln][hf * 8];
    const bf16_t* kbrow = &Wb[16384 + (size_t)o * DIM + hf * 8];
    const bf16_t* vbrow = &Wb[32768 + (size_t)o * DIM + hf * 8];
    f32x16 ka = {}, va = {};
#pragma unroll
    for (int c0 = 0; c0 < 128; c0 += 16) {
      bf16x8 af = *(const bf16x8*)&ar2[c0];
      bf16x8 kb = *(const bf16x8*)&kbrow[c0];
      bf16x8 vb = *(const bf16x8*)&vbrow[c0];
      ka = __builtin_amdgcn_mfma_f32_32x32x16_bf16(af, kb, ka, 0, 0, 0);
      va = __builtin_amdgcn_mfma_f32_32x32x16_bf16(af, vb, va, 0, 0, 0);
    }
    int hloc = o >> 4, d = o & 15;
    {
      float kb2 = k_b[o];
      size_t CB = (((size_t)b * HEADS + hloc) * NC + cid) * 512;
#pragma unroll
      for (int g = 0; g < 4; ++g)
#pragma unroll
        for (int jj = 0; jj < 4; ++jj) {
          int sl2 = 8 * g + 4 * hf + jj;
          Kp[CB + sl2 * 16 + d] = f2bf(ka[4 * g + jj] + kb2);
        }
    }
    {
      float vb2 = v_b[o];
      size_t CB = (((size_t)b * HEADS + hloc) * NC + cid) * 1024;
      uint4 w0, w1;
      w0.x = packbf2(va[0] + vb2, va[1] + vb2);
      w0.y = packbf2(va[2] + vb2, va[3] + vb2);
      w0.z = packbf2(va[4] + vb2, va[5] + vb2);
      w0.w = packbf2(va[6] + vb2, va[7] + vb2);
      w1.x = packbf2(va[8] + vb2, va[9] + vb2);
      w1.y = packbf2(va[10] + vb2, va[11] + vb2);
      w1.z = packbf2(va[12] + vb2, va[13] + vb2);
      w1.w = packbf2(va[14] + vb2, va[15] + vb2);
      *(uint4*)&Vp[CB + d * 16 + hf * 8] = w0;       // va block
      *(uint4*)&Vp[CB + 512 + d * 16 + hf * 8] = w1; // vb block
    }
    // Vp lane-16 (denominator) rows for this (b, chunk), all 8 heads
    {
      int hh = t >> 5, pos = t & 31;
      size_t addr = (((size_t)b * HEADS + hh) * NC + cid) * 1024 + 256 +
                    ((pos & 16) ? 512 : 0) + (pos & 15);
      Vp[addr] = 0x3F80;               // 1.0 bf16
    }
  } else {                           // ---- q part (C = 128) ----
    int s0 = (blockIdx.x - 50) * 32;

    // Stage 32-token x 128-channel bf16 tile, token-major (coalesced reads).
    {
      int tx = t & 31, cg = t >> 5;
      const float* xb = x + (size_t)b * DIM * NQ + s0 + tx;
#pragma unroll
      for (int it = 0; it < 8; ++it) {
        int c = 2 * cg + 16 * it;
        float a0 = xb[(size_t)c * NQ];
        float a1 = xb[(size_t)(c + 1) * NQ];
        *(unsigned*)&xs[tx][c] = packbf2(a0, a1);
      }
    }
    __syncthreads();

    const unsigned short* arow = &xs[ln][hf * 8];
    const bf16_t* brow = &Wb[(size_t)o * DIM + hf * 8];
    f32x16 acc = {};
#pragma unroll
    for (int c0 = 0; c0 < 128; c0 += 16) {
      bf16x8 af = *(const bf16x8*)&arow[c0];
      bf16x8 bf = *(const bf16x8*)&brow[c0];
      acc = __builtin_amdgcn_mfma_f32_32x32x16_bf16(af, bf, acc, 0, 0, 0);
    }
    float bv = q_b[o];
#pragma unroll
    for (int g = 0; g < 4; ++g)
#pragma unroll
      for (int jj = 0; jj < 4; ++jj) {
        int sq = s0 + 8 * g + 4 * hf + jj;
        Qb[((size_t)b * NQ + sq) * DIM + o] = f2bf((acc[4 * g + jj] + bv) * sl);
      }
  }
}

// ---------------------------------------------------------------------------
// MFMA attention, 2 q-tiles per wave, kv-split = 5 (round-4). Round-3 showed
// the 2-tile body starved on TLP (800 blocks = 3.1/CU, occupancy 16%): the
// S->exp->pack->PV chains have no co-resident waves to hide behind. Split 5
// gives 2000 blocks (7.8/CU, 31 waves/CU demand vs VGPR-84 cap of 24) at the
// cost of 10 Pb/Lsum partial slices. Exp and MFMA counts unchanged.
// grid (25, 8, 10): z = b + 2*split. block 256.
// ---------------------------------------------------------------------------
__global__ __launch_bounds__(256) void attn_split(
    const bf16_t* __restrict__ Qb, const bf16_t* __restrict__ Kp,
    const bf16_t* __restrict__ Vp, unsigned short* __restrict__ Pb,
    float* __restrict__ Lsum)
{
  const int t = threadIdx.x;
  const int ln = t & 31, hf = (t >> 5) & 1, wid = t >> 6;
  const int h = blockIdx.y;
  const int b = blockIdx.z & 1, sp = blockIdx.z >> 1;
  const int q0 = blockIdx.x * 256 + wid * 32;   // tile A
  const int q1 = q0 + 128;                      // tile B

  bf16x8 qfA = *(const bf16x8*)&Qb[((size_t)b * NQ + q0 + ln) * DIM + h * 16 + hf * 8];
  bf16x8 qfB = *(const bf16x8*)&Qb[((size_t)b * NQ + q1 + ln) * DIM + h * 16 + hf * 8];
  const int bh = b * HEADS + h;
  const bf16_t* kc = &Kp[((size_t)bh * NC + sp * CPS) * 512 + ln * 16 + hf * 8];
  const bf16_t* vc = &Vp[((size_t)bh * NC + sp * CPS) * 1024 + ln * 16 + hf * 8];

  f32x16 aA0 = {}, aA1 = {}, aB0 = {}, aB1 = {};
  const f32x16 zero = {};

  bf16x8 kf0 = *(const bf16x8*)kc;
  bf16x8 va0 = *(const bf16x8*)vc;
  bf16x8 vb0 = *(const bf16x8*)(vc + 512);
  bf16x8 kf1 = *(const bf16x8*)(kc + 512);
  bf16x8 va1 = *(const bf16x8*)(vc + 1024);
  bf16x8 vb1 = *(const bf16x8*)(vc + 1536);

  f32x16 S0a = __builtin_amdgcn_mfma_f32_32x32x16_bf16(kf0, qfA, zero, 0, 0, 0);
  f32x16 S0b = __builtin_amdgcn_mfma_f32_32x32x16_bf16(kf0, qfB, zero, 0, 0, 0);

  for (int c = 0; c < CPS; ++c) {
    int cn = (c + 2 < CPS) ? c + 2 : CPS - 1;  // 2-deep prefetch (clamped)
    bf16x8 kf2 = *(const bf16x8*)(kc + (size_t)cn * 512);
    bf16x8 va2 = *(const bf16x8*)(vc + (size_t)cn * 1024);
    bf16x8 vb2 = *(const bf16x8*)(vc + (size_t)cn * 1024 + 512);

    f32x16 S1a = __builtin_amdgcn_mfma_f32_32x32x16_bf16(kf1, qfA, zero, 0, 0, 0);
    f32x16 S1b = __builtin_amdgcn_mfma_f32_32x32x16_bf16(kf1, qfB, zero, 0, 0, 0);

    {
      BF8U f0, f1;
#pragma unroll
      for (int i = 0; i < 4; ++i) {
        f0.u[i] = packbf2(__builtin_amdgcn_exp2f(S0a[2 * i]),
                          __builtin_amdgcn_exp2f(S0a[2 * i + 1]));
        f1.u[i] = packbf2(__builtin_amdgcn_exp2f(S0a[8 + 2 * i]),
                          __builtin_amdgcn_exp2f(S0a[9 + 2 * i]));
      }
      aA0 = __builtin_amdgcn_mfma_f32_32x32x16_bf16(va0, f0.v, aA0, 0, 0, 0);
      aA1 = __builtin_amdgcn_mfma_f32_32x32x16_bf16(vb0, f1.v, aA1, 0, 0, 0);
    }
    {
      BF8U f0, f1;
#pragma unroll
      for (int i = 0; i < 4; ++i) {
        f0.u[i] = packbf2(__builtin_amdgcn_exp2f(S0b[2 * i]),
                          __builtin_amdgcn_exp2f(S0b[2 * i + 1]));
        f1.u[i] = packbf2(__builtin_amdgcn_exp2f(S0b[8 + 2 * i]),
                          __builtin_amdgcn_exp2f(S0b[9 + 2 * i]));
      }
      aB0 = __builtin_amdgcn_mfma_f32_32x32x16_bf16(va0, f0.v, aB0, 0, 0, 0);
      aB1 = __builtin_amdgcn_mfma_f32_32x32x16_bf16(vb0, f1.v, aB1, 0, 0, 0);
    }

    S0a = S1a; S0b = S1b;
    kf0 = kf1; va0 = va1; vb0 = vb1;
    kf1 = kf2; va1 = va2; vb1 = vb2;
  }

  f32x16 accA, accB;
#pragma unroll
  for (int i = 0; i < 16; ++i) { accA[i] = aA0[i] + aA1[i]; accB[i] = aB0[i] + aB1[i]; }

  // acc: col q = ln, row d = (r&3)+8*(r>>2)+4*hf. Row16 (denom) = acc[8]@hf0.
  size_t sbase = (size_t)(sp * 2 + b) * (NQ * DIM);
  {
    unsigned short* prow = &Pb[sbase + (size_t)(q0 + ln) * DIM + h * 16 + 4 * hf];
    uint2 w0, w1;
    w0.x = packbf2(accA[0], accA[1]); w0.y = packbf2(accA[2], accA[3]);
    w1.x = packbf2(accA[4], accA[5]); w1.y = packbf2(accA[6], accA[7]);
    *(uint2*)&prow[0] = w0;
    *(uint2*)&prow[8] = w1;
  }
  {
    unsigned short* prow = &Pb[sbase + (size_t)(q1 + ln) * DIM + h * 16 + 4 * hf];
    uint2 w0, w1;
    w0.x = packbf2(accB[0], accB[1]); w0.y = packbf2(accB[2], accB[3]);
    w1.x = packbf2(accB[4], accB[5]); w1.y = packbf2(accB[6], accB[7]);
    *(uint2*)&prow[0] = w0;
    *(uint2*)&prow[8] = w1;
  }
  if (!hf) {
    size_t lbase = (size_t)(sp * 2 + b) * (HEADS * NQ) + (size_t)h * NQ;
    Lsum[lbase + q0 + ln] = accA[8];
    Lsum[lbase + q1 + ln] = accB[8];
  }
}

// ---------------------------------------------------------------------------
// proj_comb: fused combine (NSPLIT halves) + reference scramble + proj GEMM.
// u32 combine loads (2 tokens/lane). Proj weights from bf16 Wb.
// grid (200,2), blk 256.
// ---------------------------------------------------------------------------
__global__ __launch_bounds__(256) void proj_comb(
    const unsigned short* __restrict__ Pb, const float* __restrict__ Lsum,
    const bf16_t* __restrict__ Wb, const float* __restrict__ p_b,
    float* __restrict__ Out)
{
  __shared__ __align__(16) unsigned short As[32][136];
  int t = threadIdx.x;
  int b = blockIdx.y;
  int s0 = blockIdx.x * 32;

  {
    int tp = t & 15, cg = t >> 4;          // token pair, 16 channel groups
#pragma unroll
    for (int it = 0; it < 8; ++it) {
      int c = cg * 8 + it;
      int f = c * NQ + s0 + 2 * tp;        // flat att index; even -> d<=14
      int n = f >> 7, hh = (f >> 4) & 7;
      float plo = 0.f, phi = 0.f, L = 0.f;
#pragma unroll
      for (int s = 0; s < NSPLIT; ++s) {
        unsigned u = *(const unsigned*)&Pb[(size_t)(2 * s + b) * (NQ * DIM) + f];
        plo += __uint_as_float(u << 16);
        phi += __uint_as_float(u & 0xFFFF0000u);
        L += Lsum[(size_t)(2 * s + b) * (HEADS * NQ) + (size_t)hh * NQ + n];
      }
      As[2 * tp][c]     = f2bf(plo / L);
      As[2 * tp + 1][c] = f2bf(phi / L);
    }
  }
  __syncthreads();

  int ln = t & 31, hf = (t >> 5) & 1, wid = t >> 6;
  int o = wid * 32 + ln;
  const bf16_t* brow = &Wb[49152 + (size_t)o * DIM + hf * 8];
  const unsigned short* arow = &As[ln][hf * 8];
  f32x16 acc = {};
#pragma unroll
  for (int c0 = 0; c0 < 128; c0 += 16) {
    bf16x8 af = *(const bf16x8*)&arow[c0];
    bf16x8 bf = *(const bf16x8*)&brow[c0];
    acc = __builtin_amdgcn_mfma_f32_32x32x16_bf16(af, bf, acc, 0, 0, 0);
  }
  float bv = p_b[o];
  float* obase = &Out[((size_t)b * DIM + o) * NQ + s0 + 4 * hf];
#pragma unroll
  for (int g = 0; g < 4; ++g) {
    float4 r;
    r.x = acc[4 * g + 0] + bv; r.y = acc[4 * g + 1] + bv;
    r.z = acc[4 * g + 2] + bv; r.w = acc[4 * g + 3] + bv;
    *(float4*)&obase[8 * g] = r;
  }
}

// ---------------------------------------------------------------------------
extern "C" void kernel_launch(void* const* d_in, const int* in_sizes, int n_in,
                              void* d_out, int out_size, void* d_ws, size_t ws_size,
                              hipStream_t stream)
{
  const float* x    = (const float*)d_in[0];
  const float* q_w  = (const float*)d_in[1];
  const float* q_b  = (const float*)d_in[2];
  const float* k_w  = (const float*)d_in[3];
  const float* k_b  = (const float*)d_in[4];
  const float* v_w  = (const float*)d_in[5];
  const float* v_b  = (const float*)d_in[6];
  const float* sr_w = (const float*)d_in[7];
  const float* sr_b = (const float*)d_in[8];
  const float* bng  = (const float*)d_in[9];
  const float* bnb  = (const float*)d_in[10];
  const float* bnm  = (const float*)d_in[11];
  const float* bnv  = (const float*)d_in[12];
  const float* p_w  = (const float*)d_in[13];
  const float* p_b  = (const float*)d_in[14];
  float* out = (float*)d_out;

  float* ws = (float*)d_ws;
  // f32-slot layout, no aliasing (~24.4 MB):
  bf16_t* Qb   = (bf16_t*)(ws);             // [0, 819200)
  bf16_t* Kp   = (bf16_t*)(ws + 819200);    // [819200, 1024000)
  bf16_t* Vp   = (bf16_t*)(ws + 1024000);   // [1024000, 1433600)
  float*  Lsum = ws + 1433600;              // [1433600, 1945600) 10 slices
  bf16_t* Pb   = (bf16_t*)(ws + 1945600);   // [1945600, 6041600) 10 slices
  bf16_t* Wb   = (bf16_t*)(ws + 6041600);   // [6041600, 6107136)

  const float sl = 0.25f * LOG2E;  // SCALE * log2(e) folded into Q

  // 1. one-time weight cast (tiny)
  wcast<<<dim3(128), dim3(256), 0, stream>>>(
      q_w, k_w, v_w, p_w, sr_w, (unsigned short*)Wb);

  // 2. fused q + sr->k->v from f32 x (LDS-staged A) + bf16 Wb rows
  mgemm_qsrkv<<<dim3(250, NBATCH), dim3(256), 0, stream>>>(
      x, Wb, q_b, sr_b, k_b, v_b, bng, bnb, bnm, bnv,
      (unsigned short*)Qb, (unsigned short*)Kp, (unsigned short*)Vp, sl);

  // 3. attention partials (kv-split = 5, 2 q-tiles/wave, shared K/V frags)
  attn_split<<<dim3(NQ / 256, HEADS, 2 * NSPLIT), dim3(256), 0, stream>>>(
      Qb, Kp, Vp, (unsigned short*)Pb, Lsum);

  // 4. combine + scramble + proj -> f32 chan-major final output (B,128,80,80)
  proj_comb<<<dim3(200, NBATCH), dim3(256), 0, stream>>>(
      (const unsigned short*)Pb, Lsum, Wb, p_b, out);
}